// Round 1
// baseline (397.678 us; speedup 1.0000x reference)
//
#include <hip/hip_runtime.h>

#define SLEN 2048
#define DH 64
#define QT 64
#define KVB 64
#define LDK 72   // padded LDS row pitch (bf16 elems): 144B rows, 16B-aligned, 2-way banks only
#define NEGBIG (-1e30f)

typedef __attribute__((ext_vector_type(8))) short bf16x8;
typedef __attribute__((ext_vector_type(4))) float f32x4;

__device__ __forceinline__ ushort f2bf(float f) {
  union { float f; unsigned int u; } v; v.f = f;
  unsigned int r = v.u + 0x7fffu + ((v.u >> 16) & 1u);  // RNE
  return (ushort)(r >> 16);
}

__global__ __launch_bounds__(256) void attn_fwd(
    const float* __restrict__ Qg, const float* __restrict__ Kg,
    const float* __restrict__ Vg, float* __restrict__ Og) {
  __shared__ ushort Kl[KVB * LDK];        // K tile, bf16 row-major [kv][d]
  __shared__ ushort Vt[DH * LDK];         // V tile, bf16 transposed [d][kv]
  __shared__ ushort Pl[4 * 16 * LDK];     // per-wave P stage [wave][q16][kv64]

  const int qt   = blockIdx.x;
  const int tid  = threadIdx.x;
  const int w    = tid >> 6;
  const int lane = tid & 63;
  const int lg   = lane >> 4;   // lane group 0..3
  const int lr   = lane & 15;

  const size_t hoff = (size_t)blockIdx.y * SLEN * DH;
  const float* Qh = Qg + hoff;
  const float* Kh = Kg + hoff;
  const float* Vh = Vg + hoff;
  float*       Oh = Og + hoff;

  const int qbase = qt * QT + w * 16;

  // ---- Q fragments (A-operand: row=lr, k=lg*8+j), pre-scaled by 1/sqrt(D) ----
  bf16x8 qf[2];
  {
    const float* qrow = Qh + (size_t)(qbase + lr) * DH;
    const float s = 0.125f;
#pragma unroll
    for (int h = 0; h < 2; ++h) {
      const int d0 = h * 32 + lg * 8;
      float4 a = *reinterpret_cast<const float4*>(qrow + d0);
      float4 b = *reinterpret_cast<const float4*>(qrow + d0 + 4);
      bf16x8 t;
      t[0] = (short)f2bf(a.x * s); t[1] = (short)f2bf(a.y * s);
      t[2] = (short)f2bf(a.z * s); t[3] = (short)f2bf(a.w * s);
      t[4] = (short)f2bf(b.x * s); t[5] = (short)f2bf(b.y * s);
      t[6] = (short)f2bf(b.z * s); t[7] = (short)f2bf(b.w * s);
      qf[h] = t;
    }
  }

  f32x4 oacc[4];
#pragma unroll
  for (int dc = 0; dc < 4; ++dc) oacc[dc] = (f32x4)0.0f;
  float mrow[4], lrow[4];
#pragma unroll
  for (int r = 0; r < 4; ++r) { mrow[r] = -3.0e38f; lrow[r] = 0.0f; }

  const int nkv = qt + 1;
  for (int kvb = 0; kvb < nkv; ++kvb) {
    __syncthreads();
    // ---- stage K (row-major) and V (transposed) as bf16 ----
#pragma unroll
    for (int i = 0; i < 4; ++i) {
      const int n   = tid + i * 256;       // 0..1023 float4-chunks
      const int row = n >> 4;              // kv row 0..63
      const int c4  = (n & 15) << 2;       // d col 0..60
      const size_t goff = (size_t)(kvb * KVB + row) * DH + c4;
      float4 k4 = *reinterpret_cast<const float4*>(Kh + goff);
      ushort4 u;
      u.x = f2bf(k4.x); u.y = f2bf(k4.y); u.z = f2bf(k4.z); u.w = f2bf(k4.w);
      *reinterpret_cast<ushort4*>(&Kl[row * LDK + c4]) = u;
      float4 v4 = *reinterpret_cast<const float4*>(Vh + goff);
      Vt[(c4 + 0) * LDK + row] = f2bf(v4.x);
      Vt[(c4 + 1) * LDK + row] = f2bf(v4.y);
      Vt[(c4 + 2) * LDK + row] = f2bf(v4.z);
      Vt[(c4 + 3) * LDK + row] = f2bf(v4.w);
    }
    __syncthreads();

    // ---- S = Q K^T  (4 kv-chunks of 16, 2 d-halves of 32) ----
    f32x4 sfr[4];
#pragma unroll
    for (int c = 0; c < 4; ++c) sfr[c] = (f32x4)0.0f;
#pragma unroll
    for (int c = 0; c < 4; ++c) {
#pragma unroll
      for (int h = 0; h < 2; ++h) {
        bf16x8 kf = *reinterpret_cast<const bf16x8*>(
            &Kl[(c * 16 + lr) * LDK + h * 32 + lg * 8]);
        sfr[c] = __builtin_amdgcn_mfma_f32_16x16x32_bf16(qf[h], kf, sfr[c], 0, 0, 0);
      }
    }

    // ---- causal mask (diagonal block only) ----
    if (kvb == qt) {
#pragma unroll
      for (int c = 0; c < 4; ++c)
#pragma unroll
        for (int r = 0; r < 4; ++r) {
          const int kv = kvb * KVB + c * 16 + lr;
          const int q  = qbase + lg * 4 + r;
          if (kv > q) sfr[c][r] = NEGBIG;
        }
    }

    // ---- online softmax (16-lane butterfly; groups share q rows) ----
    float mx[4];
#pragma unroll
    for (int r = 0; r < 4; ++r)
      mx[r] = fmaxf(fmaxf(sfr[0][r], sfr[1][r]), fmaxf(sfr[2][r], sfr[3][r]));
#pragma unroll
    for (int off = 8; off >= 1; off >>= 1)
#pragma unroll
      for (int r = 0; r < 4; ++r)
        mx[r] = fmaxf(mx[r], __shfl_xor(mx[r], off));

    float sc[4];
#pragma unroll
    for (int r = 0; r < 4; ++r) {
      const float mn = fmaxf(mrow[r], mx[r]);
      sc[r] = __expf(mrow[r] - mn);
      mrow[r] = mn;
    }
    float rs[4];
#pragma unroll
    for (int r = 0; r < 4; ++r) rs[r] = 0.0f;
#pragma unroll
    for (int c = 0; c < 4; ++c)
#pragma unroll
      for (int r = 0; r < 4; ++r) {
        const float p = __expf(sfr[c][r] - mrow[r]);
        sfr[c][r] = p;
        rs[r] += p;
      }
#pragma unroll
    for (int off = 8; off >= 1; off >>= 1)
#pragma unroll
      for (int r = 0; r < 4; ++r)
        rs[r] += __shfl_xor(rs[r], off);
#pragma unroll
    for (int r = 0; r < 4; ++r) lrow[r] = lrow[r] * sc[r] + rs[r];
#pragma unroll
    for (int dc = 0; dc < 4; ++dc)
#pragma unroll
      for (int r = 0; r < 4; ++r) oacc[dc][r] *= sc[r];

    // ---- P: S-frag layout -> A-frag layout via per-wave LDS ----
    ushort* Pw = &Pl[w * 16 * LDK];
#pragma unroll
    for (int c = 0; c < 4; ++c)
#pragma unroll
      for (int r = 0; r < 4; ++r)
        Pw[(lg * 4 + r) * LDK + c * 16 + lr] = f2bf(sfr[c][r]);

    bf16x8 pf[2];
#pragma unroll
    for (int h = 0; h < 2; ++h)
      pf[h] = *reinterpret_cast<const bf16x8*>(&Pw[lr * LDK + h * 32 + lg * 8]);

    // ---- O += P V ----
#pragma unroll
    for (int dc = 0; dc < 4; ++dc) {
#pragma unroll
      for (int h = 0; h < 2; ++h) {
        bf16x8 vf = *reinterpret_cast<const bf16x8*>(
            &Vt[(dc * 16 + lr) * LDK + h * 32 + lg * 8]);
        oacc[dc] = __builtin_amdgcn_mfma_f32_16x16x32_bf16(pf[h], vf, oacc[dc], 0, 0, 0);
      }
    }
  }

  // ---- epilogue: normalize and store ----
#pragma unroll
  for (int dc = 0; dc < 4; ++dc)
#pragma unroll
    for (int r = 0; r < 4; ++r) {
      const int q = qbase + lg * 4 + r;
      Oh[(size_t)q * DH + dc * 16 + lr] = oacc[dc][r] / lrow[r];
    }
}

extern "C" void kernel_launch(void* const* d_in, const int* in_sizes, int n_in,
                              void* d_out, int out_size, void* d_ws, size_t ws_size,
                              hipStream_t stream) {
  const float* q = (const float*)d_in[0];
  const float* k = (const float*)d_in[1];
  const float* v = (const float*)d_in[2];
  // d_in[3] is the causal tril mask — implemented analytically, not read.
  float* out = (float*)d_out;
  dim3 grid(SLEN / QT, 4 * 16);
  attn_fwd<<<grid, 256, 0, stream>>>(q, k, v, out);
}

// Round 2
// 271.929 us; speedup vs baseline: 1.4624x; 1.4624x over previous
//
#include <hip/hip_runtime.h>

#define SLEN 2048
#define DH 64
#define NH 64        // B*H = 4*16
#define QT 64
#define KVB 64
#define NT 32        // SLEN / KVB
#define LDK 72       // fallback-kernel LDS pitch
#define PLD 68       // P-stage pitch (ushorts): conflict-free store+read
#define NEGBIG (-1e30f)

typedef __attribute__((ext_vector_type(8))) short bf16x8;
typedef __attribute__((ext_vector_type(8))) unsigned short u16x8;
typedef __attribute__((ext_vector_type(4))) float f32x4;

__device__ __forceinline__ ushort f2bf(float f) {
  union { float f; unsigned int u; } v; v.f = f;
  unsigned int r = v.u + 0x7fffu + ((v.u >> 16) & 1u);  // RNE
  return (ushort)(r >> 16);
}

__device__ __forceinline__ void gload16(const ushort* g, ushort* l) {
  __builtin_amdgcn_global_load_lds(
      (const __attribute__((address_space(1))) void*)g,
      (__attribute__((address_space(3))) void*)l, 16, 0, 0);
}

// ---------------- pre-pass: K -> bf16, tile-blocked, XOR-swizzled ----------------
// ws tile layout (4096 ushorts per 64x64 tile): chunk(r,c) = K[r][c*8..c*8+7]
// stored at ushort offset r*64 + ((c ^ (r&7)) * 8).
__global__ __launch_bounds__(256) void prep_k(const float* __restrict__ Kg,
                                              ushort* __restrict__ wsK) {
  const int tile = blockIdx.x, head = blockIdx.y, tid = threadIdx.x;
  const float* src = Kg + ((size_t)head * SLEN + (size_t)tile * KVB) * DH;
  ushort* dst = wsK + ((size_t)head * NT + tile) * (KVB * DH);
#pragma unroll
  for (int i = 0; i < 2; ++i) {
    const int id = tid + i * 256;
    const int r = id >> 3, c = id & 7;
    float4 a = *reinterpret_cast<const float4*>(src + r * DH + c * 8);
    float4 b = *reinterpret_cast<const float4*>(src + r * DH + c * 8 + 4);
    u16x8 t;
    t[0] = f2bf(a.x); t[1] = f2bf(a.y); t[2] = f2bf(a.z); t[3] = f2bf(a.w);
    t[4] = f2bf(b.x); t[5] = f2bf(b.y); t[6] = f2bf(b.z); t[7] = f2bf(b.w);
    *reinterpret_cast<u16x8*>(dst + r * DH + ((c ^ (r & 7)) * 8)) = t;
  }
}

// ---------------- pre-pass: V -> bf16 TRANSPOSED, tile-blocked, swizzled --------
// chunk(d,c) = V[c*8..c*8+7][d] at ushort offset d*64 + ((c ^ (d&7)) * 8).
__global__ __launch_bounds__(256) void prep_v(const float* __restrict__ Vg,
                                              ushort* __restrict__ wsV) {
  __shared__ float Vl[KVB][DH + 1];
  const int tile = blockIdx.x, head = blockIdx.y, tid = threadIdx.x;
  const float* src = Vg + ((size_t)head * SLEN + (size_t)tile * KVB) * DH;
#pragma unroll
  for (int i = 0; i < 4; ++i) {
    const int n = tid + i * 256;
    const int row = n >> 4, c4 = (n & 15) << 2;
    *reinterpret_cast<float4*>(&Vl[row][c4]) =
        *reinterpret_cast<const float4*>(src + row * DH + c4);
  }
  __syncthreads();
  ushort* dst = wsV + ((size_t)head * NT + tile) * (KVB * DH);
#pragma unroll
  for (int i = 0; i < 2; ++i) {
    const int id = tid + i * 256;
    const int d = id >> 3, c = id & 7;
    u16x8 t;
#pragma unroll
    for (int j = 0; j < 8; ++j) t[j] = f2bf(Vl[c * 8 + j][d]);
    *reinterpret_cast<u16x8*>(dst + d * DH + ((c ^ (d & 7)) * 8)) = t;
  }
}

// ---------------- main: flash attention, dbuf global_load_lds staging -----------
__global__ __launch_bounds__(256) void attn_fwd2(
    const float* __restrict__ Qg, const ushort* __restrict__ wsK,
    const ushort* __restrict__ wsV, float* __restrict__ Og) {
  __shared__ ushort kvl[2][8192];        // [buf][ K:0..4095 | V:4096..8191 ]
  __shared__ ushort Pl[4][16 * PLD];

  const int qt   = (NT - 1) - blockIdx.x;   // longest blocks dispatch first
  const int head = blockIdx.y;
  const int tid  = threadIdx.x;
  const int w    = tid >> 6;
  const int lane = tid & 63;
  const int lg   = lane >> 4;
  const int lr   = lane & 15;

  const float*  Qh    = Qg + (size_t)head * SLEN * DH;
  float*        Oh    = Og + (size_t)head * SLEN * DH;
  const ushort* kbase = wsK + (size_t)head * (NT * KVB * DH);
  const ushort* vbase = wsV + (size_t)head * (NT * KVB * DH);

  const int qbase = qt * QT + w * 16;
  const int so    = w * 1024;   // this wave's 2KB staging segment (ushort offset)
  const int lo    = lane * 8;   // lane's 16B within each 1KB chunk

  // stage tile t into kvl[buf]: 4 x 16B-wide global_load_lds per wave
#define STAGE(buf, t)                                                        \
  do {                                                                       \
    const ushort* ks_ = kbase + (size_t)(t) * 4096 + so + lo;                \
    const ushort* vs_ = vbase + (size_t)(t) * 4096 + so + lo;                \
    gload16(ks_,       &kvl[buf][so + lo]);                                  \
    gload16(ks_ + 512, &kvl[buf][so + 512 + lo]);                            \
    gload16(vs_,       &kvl[buf][4096 + so + lo]);                           \
    gload16(vs_ + 512, &kvl[buf][4096 + so + 512 + lo]);                     \
  } while (0)

  STAGE(0, 0);

  // ---- Q fragments (A-operand: row=lr, k=lg*8+j), pre-scaled by 1/sqrt(D) ----
  bf16x8 qf[2];
  {
    const float* qrow = Qh + (size_t)(qbase + lr) * DH;
    const float s = 0.125f;
#pragma unroll
    for (int h = 0; h < 2; ++h) {
      const int d0 = h * 32 + lg * 8;
      float4 a = *reinterpret_cast<const float4*>(qrow + d0);
      float4 b = *reinterpret_cast<const float4*>(qrow + d0 + 4);
      bf16x8 t;
      t[0] = (short)f2bf(a.x * s); t[1] = (short)f2bf(a.y * s);
      t[2] = (short)f2bf(a.z * s); t[3] = (short)f2bf(a.w * s);
      t[4] = (short)f2bf(b.x * s); t[5] = (short)f2bf(b.y * s);
      t[6] = (short)f2bf(b.z * s); t[7] = (short)f2bf(b.w * s);
      qf[h] = t;
    }
  }

  f32x4 oacc[4];
#pragma unroll
  for (int dc = 0; dc < 4; ++dc) oacc[dc] = (f32x4)0.0f;
  float mrow[4], lrow[4];
#pragma unroll
  for (int r = 0; r < 4; ++r) { mrow[r] = -3.0e38f; lrow[r] = 0.0f; }

  __syncthreads();   // drains vmcnt(0): tile 0 resident

  int cur = 0;
  for (int t = 0; t <= qt; ++t) {
    if (t < qt) STAGE(cur ^ 1, t + 1);   // prefetch next tile (other buffer)

    const ushort* Kl = kvl[cur];
    const ushort* Vt = kvl[cur] + 4096;

    // ---- S = Q K^T ----
    f32x4 sfr[4];
#pragma unroll
    for (int c = 0; c < 4; ++c) sfr[c] = (f32x4)0.0f;
#pragma unroll
    for (int c = 0; c < 4; ++c) {
      const int r = c * 16 + lr;
#pragma unroll
      for (int h = 0; h < 2; ++h) {
        bf16x8 kf = *reinterpret_cast<const bf16x8*>(
            &Kl[r * 64 + (((h * 4 + lg) ^ (lr & 7)) * 8)]);
        sfr[c] = __builtin_amdgcn_mfma_f32_16x16x32_bf16(qf[h], kf, sfr[c], 0, 0, 0);
      }
    }

    // ---- causal mask (diagonal block only) ----
    if (t == qt) {
#pragma unroll
      for (int c = 0; c < 4; ++c)
#pragma unroll
        for (int r = 0; r < 4; ++r) {
          const int kv = t * KVB + c * 16 + lr;
          const int q  = qbase + lg * 4 + r;
          if (kv > q) sfr[c][r] = NEGBIG;
        }
    }

    // ---- online softmax (16-lane butterfly; groups share q rows) ----
    float mx[4];
#pragma unroll
    for (int r = 0; r < 4; ++r)
      mx[r] = fmaxf(fmaxf(sfr[0][r], sfr[1][r]), fmaxf(sfr[2][r], sfr[3][r]));
#pragma unroll
    for (int off = 8; off >= 1; off >>= 1)
#pragma unroll
      for (int r = 0; r < 4; ++r)
        mx[r] = fmaxf(mx[r], __shfl_xor(mx[r], off));

    float sc[4];
#pragma unroll
    for (int r = 0; r < 4; ++r) {
      const float mn = fmaxf(mrow[r], mx[r]);
      sc[r] = __expf(mrow[r] - mn);
      mrow[r] = mn;
    }
    float rs[4];
#pragma unroll
    for (int r = 0; r < 4; ++r) rs[r] = 0.0f;
#pragma unroll
    for (int c = 0; c < 4; ++c)
#pragma unroll
      for (int r = 0; r < 4; ++r) {
        const float p = __expf(sfr[c][r] - mrow[r]);
        sfr[c][r] = p;
        rs[r] += p;
      }
#pragma unroll
    for (int off = 8; off >= 1; off >>= 1)
#pragma unroll
      for (int r = 0; r < 4; ++r)
        rs[r] += __shfl_xor(rs[r], off);
#pragma unroll
    for (int r = 0; r < 4; ++r) lrow[r] = lrow[r] * sc[r] + rs[r];
#pragma unroll
    for (int dc = 0; dc < 4; ++dc)
#pragma unroll
      for (int r = 0; r < 4; ++r) oacc[dc][r] *= sc[r];

    // ---- P: S-frag layout -> A-frag layout via per-wave LDS ----
    ushort* Pw = Pl[w];
#pragma unroll
    for (int c = 0; c < 4; ++c)
#pragma unroll
      for (int r = 0; r < 4; ++r)
        Pw[(lg * 4 + r) * PLD + c * 16 + lr] = f2bf(sfr[c][r]);

    bf16x8 pf[2];
#pragma unroll
    for (int h = 0; h < 2; ++h)
      pf[h] = *reinterpret_cast<const bf16x8*>(&Pw[lr * PLD + (h * 4 + lg) * 8]);

    // ---- O += P V ----
#pragma unroll
    for (int dc = 0; dc < 4; ++dc) {
      const int d = dc * 16 + lr;
#pragma unroll
      for (int h = 0; h < 2; ++h) {
        bf16x8 vf = *reinterpret_cast<const bf16x8*>(
            &Vt[d * 64 + (((h * 4 + lg) ^ (lr & 7)) * 8)]);
        oacc[dc] = __builtin_amdgcn_mfma_f32_16x16x32_bf16(pf[h], vf, oacc[dc], 0, 0, 0);
      }
    }

    __syncthreads();   // waits vmcnt(0) (prefetch landed) + all reads of cur done
    cur ^= 1;
  }
#undef STAGE

  // ---- epilogue: normalize and store ----
#pragma unroll
  for (int dc = 0; dc < 4; ++dc)
#pragma unroll
    for (int r = 0; r < 4; ++r) {
      const int q = qbase + lg * 4 + r;
      Oh[(size_t)q * DH + dc * 16 + lr] = oacc[dc][r] / lrow[r];
    }
}

// ---------------- fallback (round-1 kernel) if ws too small ---------------------
__global__ __launch_bounds__(256) void attn_fwd(
    const float* __restrict__ Qg, const float* __restrict__ Kg,
    const float* __restrict__ Vg, float* __restrict__ Og) {
  __shared__ ushort Kl[KVB * LDK];
  __shared__ ushort Vt[DH * LDK];
  __shared__ ushort Pl[4 * 16 * LDK];

  const int qt   = (NT - 1) - blockIdx.x;
  const int tid  = threadIdx.x;
  const int w    = tid >> 6;
  const int lane = tid & 63;
  const int lg   = lane >> 4;
  const int lr   = lane & 15;

  const size_t hoff = (size_t)blockIdx.y * SLEN * DH;
  const float* Qh = Qg + hoff;
  const float* Kh = Kg + hoff;
  const float* Vh = Vg + hoff;
  float*       Oh = Og + hoff;

  const int qbase = qt * QT + w * 16;

  bf16x8 qf[2];
  {
    const float* qrow = Qh + (size_t)(qbase + lr) * DH;
    const float s = 0.125f;
#pragma unroll
    for (int h = 0; h < 2; ++h) {
      const int d0 = h * 32 + lg * 8;
      float4 a = *reinterpret_cast<const float4*>(qrow + d0);
      float4 b = *reinterpret_cast<const float4*>(qrow + d0 + 4);
      bf16x8 t;
      t[0] = (short)f2bf(a.x * s); t[1] = (short)f2bf(a.y * s);
      t[2] = (short)f2bf(a.z * s); t[3] = (short)f2bf(a.w * s);
      t[4] = (short)f2bf(b.x * s); t[5] = (short)f2bf(b.y * s);
      t[6] = (short)f2bf(b.z * s); t[7] = (short)f2bf(b.w * s);
      qf[h] = t;
    }
  }

  f32x4 oacc[4];
#pragma unroll
  for (int dc = 0; dc < 4; ++dc) oacc[dc] = (f32x4)0.0f;
  float mrow[4], lrow[4];
#pragma unroll
  for (int r = 0; r < 4; ++r) { mrow[r] = -3.0e38f; lrow[r] = 0.0f; }

  const int nkv = qt + 1;
  for (int kvb = 0; kvb < nkv; ++kvb) {
    __syncthreads();
#pragma unroll
    for (int i = 0; i < 4; ++i) {
      const int n   = tid + i * 256;
      const int row = n >> 4;
      const int c4  = (n & 15) << 2;
      const size_t goff = (size_t)(kvb * KVB + row) * DH + c4;
      float4 k4 = *reinterpret_cast<const float4*>(Kh + goff);
      ushort4 u;
      u.x = f2bf(k4.x); u.y = f2bf(k4.y); u.z = f2bf(k4.z); u.w = f2bf(k4.w);
      *reinterpret_cast<ushort4*>(&Kl[row * LDK + c4]) = u;
      float4 v4 = *reinterpret_cast<const float4*>(Vh + goff);
      Vt[(c4 + 0) * LDK + row] = f2bf(v4.x);
      Vt[(c4 + 1) * LDK + row] = f2bf(v4.y);
      Vt[(c4 + 2) * LDK + row] = f2bf(v4.z);
      Vt[(c4 + 3) * LDK + row] = f2bf(v4.w);
    }
    __syncthreads();

    f32x4 sfr[4];
#pragma unroll
    for (int c = 0; c < 4; ++c) sfr[c] = (f32x4)0.0f;
#pragma unroll
    for (int c = 0; c < 4; ++c) {
#pragma unroll
      for (int h = 0; h < 2; ++h) {
        bf16x8 kf = *reinterpret_cast<const bf16x8*>(
            &Kl[(c * 16 + lr) * LDK + h * 32 + lg * 8]);
        sfr[c] = __builtin_amdgcn_mfma_f32_16x16x32_bf16(qf[h], kf, sfr[c], 0, 0, 0);
      }
    }

    if (kvb == qt) {
#pragma unroll
      for (int c = 0; c < 4; ++c)
#pragma unroll
        for (int r = 0; r < 4; ++r) {
          const int kv = kvb * KVB + c * 16 + lr;
          const int q  = qbase + lg * 4 + r;
          if (kv > q) sfr[c][r] = NEGBIG;
        }
    }

    float mx[4];
#pragma unroll
    for (int r = 0; r < 4; ++r)
      mx[r] = fmaxf(fmaxf(sfr[0][r], sfr[1][r]), fmaxf(sfr[2][r], sfr[3][r]));
#pragma unroll
    for (int off = 8; off >= 1; off >>= 1)
#pragma unroll
      for (int r = 0; r < 4; ++r)
        mx[r] = fmaxf(mx[r], __shfl_xor(mx[r], off));

    float sc[4];
#pragma unroll
    for (int r = 0; r < 4; ++r) {
      const float mn = fmaxf(mrow[r], mx[r]);
      sc[r] = __expf(mrow[r] - mn);
      mrow[r] = mn;
    }
    float rs[4];
#pragma unroll
    for (int r = 0; r < 4; ++r) rs[r] = 0.0f;
#pragma unroll
    for (int c = 0; c < 4; ++c)
#pragma unroll
      for (int r = 0; r < 4; ++r) {
        const float p = __expf(sfr[c][r] - mrow[r]);
        sfr[c][r] = p;
        rs[r] += p;
      }
#pragma unroll
    for (int off = 8; off >= 1; off >>= 1)
#pragma unroll
      for (int r = 0; r < 4; ++r)
        rs[r] += __shfl_xor(rs[r], off);
#pragma unroll
    for (int r = 0; r < 4; ++r) lrow[r] = lrow[r] * sc[r] + rs[r];
#pragma unroll
    for (int dc = 0; dc < 4; ++dc)
#pragma unroll
      for (int r = 0; r < 4; ++r) oacc[dc][r] *= sc[r];

    ushort* Pw = &Pl[w * 16 * LDK];
#pragma unroll
    for (int c = 0; c < 4; ++c)
#pragma unroll
      for (int r = 0; r < 4; ++r)
        Pw[(lg * 4 + r) * LDK + c * 16 + lr] = f2bf(sfr[c][r]);

    bf16x8 pf[2];
#pragma unroll
    for (int h = 0; h < 2; ++h)
      pf[h] = *reinterpret_cast<const bf16x8*>(&Pw[lr * LDK + h * 32 + lg * 8]);

#pragma unroll
    for (int dc = 0; dc < 4; ++dc) {
#pragma unroll
      for (int h = 0; h < 2; ++h) {
        bf16x8 vf = *reinterpret_cast<const bf16x8*>(
            &Vt[(dc * 16 + lr) * LDK + h * 32 + lg * 8]);
        oacc[dc] = __builtin_amdgcn_mfma_f32_16x16x32_bf16(pf[h], vf, oacc[dc], 0, 0, 0);
      }
    }
  }

#pragma unroll
  for (int dc = 0; dc < 4; ++dc)
#pragma unroll
    for (int r = 0; r < 4; ++r) {
      const int q = qbase + lg * 4 + r;
      Oh[(size_t)q * DH + dc * 16 + lr] = oacc[dc][r] / lrow[r];
    }
}

extern "C" void kernel_launch(void* const* d_in, const int* in_sizes, int n_in,
                              void* d_out, int out_size, void* d_ws, size_t ws_size,
                              hipStream_t stream) {
  const float* q = (const float*)d_in[0];
  const float* k = (const float*)d_in[1];
  const float* v = (const float*)d_in[2];
  // d_in[3] is the causal tril mask — implemented analytically, not read.
  float* out = (float*)d_out;

  const size_t per = (size_t)NH * SLEN * DH;          // elements per tensor
  const size_t need = 2 * per * sizeof(ushort);       // ~33.6 MB
  dim3 grid(NT, NH);
  if (ws_size >= need) {
    ushort* wsK = (ushort*)d_ws;
    ushort* wsV = wsK + per;
    prep_k<<<grid, 256, 0, stream>>>(k, wsK);
    prep_v<<<grid, 256, 0, stream>>>(v, wsV);
    attn_fwd2<<<grid, 256, 0, stream>>>(q, wsK, wsV, out);
  } else {
    attn_fwd<<<grid, 256, 0, stream>>>(q, k, v, out);
  }
}

// Round 3
// 131.574 us; speedup vs baseline: 3.0225x; 2.0667x over previous
//
#include <hip/hip_runtime.h>

#define SLEN 2048
#define DH 64
#define NH 64        // B*H
#define KVB 64
#define NT 32        // SLEN / KVB
#define QTB 256      // q rows per block (8 waves x 32)
#define NQB (SLEN / QTB)
#define NEGBIG (-1e30f)
#define SCALE 0.18033688011112042f   // 0.125 * log2(e)  (softmax in exp2 domain)

typedef __attribute__((ext_vector_type(8))) short bf16x8;
typedef __attribute__((ext_vector_type(8))) unsigned short u16x8;
typedef __attribute__((ext_vector_type(16))) float f32x16;
typedef __attribute__((ext_vector_type(4))) unsigned int u32x4;

__device__ __forceinline__ ushort f2bf(float f) {
  union { float f; unsigned int u; } v; v.f = f;
  unsigned int r = v.u + 0x7fffu + ((v.u >> 16) & 1u);  // RNE
  return (ushort)(r >> 16);
}

__device__ __forceinline__ unsigned int cvtpk(float lo, float hi2) {
  unsigned int r;
  asm("v_cvt_pk_bf16_f32 %0, %1, %2" : "=v"(r) : "v"(lo), "v"(hi2));
  return r;
}

__device__ __forceinline__ void gload16(const ushort* g, ushort* l) {
  __builtin_amdgcn_global_load_lds(
      (const __attribute__((address_space(1))) void*)g,
      (__attribute__((address_space(3))) void*)l, 16, 0, 0);
}

// ---- pre-pass: K -> bf16 tiles, chunk(r,c)=K[r][c*8..+7] at r*64 + ((c^(r&7))*8)
__global__ __launch_bounds__(256) void prep_k(const float* __restrict__ Kg,
                                              ushort* __restrict__ wsK) {
  const int tile = blockIdx.x, head = blockIdx.y, tid = threadIdx.x;
  const float* src = Kg + ((size_t)head * SLEN + (size_t)tile * KVB) * DH;
  ushort* dst = wsK + ((size_t)head * NT + tile) * (KVB * DH);
#pragma unroll
  for (int i = 0; i < 2; ++i) {
    const int id = tid + i * 256;
    const int r = id >> 3, c = id & 7;
    float4 a = *reinterpret_cast<const float4*>(src + r * DH + c * 8);
    float4 b = *reinterpret_cast<const float4*>(src + r * DH + c * 8 + 4);
    u16x8 t;
    t[0] = f2bf(a.x); t[1] = f2bf(a.y); t[2] = f2bf(a.z); t[3] = f2bf(a.w);
    t[4] = f2bf(b.x); t[5] = f2bf(b.y); t[6] = f2bf(b.z); t[7] = f2bf(b.w);
    *reinterpret_cast<u16x8*>(dst + r * DH + ((c ^ (r & 7)) * 8)) = t;
  }
}

// ---- pre-pass: V -> bf16 TRANSPOSED tiles, chunk(d,c)=V[c*8..+7][d] swizzled
__global__ __launch_bounds__(256) void prep_v(const float* __restrict__ Vg,
                                              ushort* __restrict__ wsV) {
  __shared__ float Vl[KVB][DH + 1];
  const int tile = blockIdx.x, head = blockIdx.y, tid = threadIdx.x;
  const float* src = Vg + ((size_t)head * SLEN + (size_t)tile * KVB) * DH;
#pragma unroll
  for (int i = 0; i < 4; ++i) {
    const int n = tid + i * 256;
    const int row = n >> 4, c4 = (n & 15) << 2;
    *reinterpret_cast<float4*>(&Vl[row][c4]) =
        *reinterpret_cast<const float4*>(src + row * DH + c4);
  }
  __syncthreads();
  ushort* dst = wsV + ((size_t)head * NT + tile) * (KVB * DH);
#pragma unroll
  for (int i = 0; i < 2; ++i) {
    const int id = tid + i * 256;
    const int d = id >> 3, c = id & 7;
    u16x8 t;
#pragma unroll
    for (int j = 0; j < 8; ++j) t[j] = f2bf(Vl[c * 8 + j][d]);
    *reinterpret_cast<u16x8*>(dst + d * DH + ((c ^ (d & 7)) * 8)) = t;
  }
}

// ---- main: 8-wave swapped-QK^T flash attention, 32x32x16 MFMA ----
__global__ __launch_bounds__(512, 2) void attn_fwd3(
    const float* __restrict__ Qg, const ushort* __restrict__ wsK,
    const ushort* __restrict__ wsV, float* __restrict__ Og) {
  // staging: 2 bufs x (K 8KB + V 8KB) = 32KB; epilogue transpose: 36KB (union)
  __shared__ __align__(16) float smem[9216];
  ushort* stg = (ushort*)smem;

  const int qbi  = (NQB - 1) - blockIdx.x;   // big (late-diagonal) blocks first
  const int head = blockIdx.y;
  const int tid  = threadIdx.x;
  const int w    = tid >> 6;
  const int lane = tid & 63;
  const int hi   = lane >> 5;   // 0/1: which half of the 64-lane wave
  const int ql   = lane & 31;   // this lane's q column (and kv/d row for A-ops)

  const int qb    = qbi * QTB;
  const int qw0   = qb + w * 32;      // wave's first q row
  const int nt    = (qb >> 6) + 4;    // tiles staged by the block
  const int tlast = qw0 >> 6;         // wave's last compute tile (diag)

  const float*  Qh    = Qg + (size_t)head * SLEN * DH;
  float*        Oh    = Og + (size_t)head * SLEN * DH;
  const ushort* kbase = wsK + (size_t)head * (NT * KVB * DH);
  const ushort* vbase = wsV + (size_t)head * (NT * KVB * DH);

#define STAGE(buf, t)                                                          \
  do {                                                                         \
    gload16(kbase + (size_t)(t) * 4096 + tid * 8, stg + (buf) * 8192 + tid * 8);\
    gload16(vbase + (size_t)(t) * 4096 + tid * 8,                              \
            stg + (buf) * 8192 + 4096 + tid * 8);                              \
  } while (0)

  STAGE(0, 0);

  // Q as B-operand of swapped QK^T: lane holds col q=ql, k = ks*16 + hi*8 + jj
  bf16x8 qf[4];
  {
    const float* qrow = Qh + (size_t)(qw0 + ql) * DH;
#pragma unroll
    for (int ks = 0; ks < 4; ++ks) {
      const int d0 = ks * 16 + hi * 8;
      float4 a = *reinterpret_cast<const float4*>(qrow + d0);
      float4 b = *reinterpret_cast<const float4*>(qrow + d0 + 4);
      bf16x8 t;
      t[0] = (short)f2bf(a.x * SCALE); t[1] = (short)f2bf(a.y * SCALE);
      t[2] = (short)f2bf(a.z * SCALE); t[3] = (short)f2bf(a.w * SCALE);
      t[4] = (short)f2bf(b.x * SCALE); t[5] = (short)f2bf(b.y * SCALE);
      t[6] = (short)f2bf(b.z * SCALE); t[7] = (short)f2bf(b.w * SCALE);
      qf[ks] = t;
    }
  }

  f32x16 oacc0 = (f32x16)0.0f, oacc1 = (f32x16)0.0f;  // O^T[d][q], d-halves
  float m = -3.0e38f, l = 0.0f;

  __syncthreads();   // tile 0 resident

  int cur = 0;
  for (int t = 0; t < nt; ++t) {
    if (t + 1 < nt) STAGE(cur ^ 1, t + 1);

    if (t <= tlast) {
      const ushort* Kl = stg + cur * 8192;
      const ushort* Vl = Kl + 4096;

      // ---- S^T[kv][q] = K · Q^T  (2 kv-halves x 4 d-slots) ----
      f32x16 s0 = (f32x16)0.0f, s1 = (f32x16)0.0f;
#pragma unroll
      for (int ks = 0; ks < 4; ++ks) {
        const int c = ((ks * 2 + hi) ^ (ql & 7)) * 8;
        bf16x8 kf0 = *reinterpret_cast<const bf16x8*>(Kl + ql * 64 + c);
        bf16x8 kf1 = *reinterpret_cast<const bf16x8*>(Kl + (32 + ql) * 64 + c);
        s0 = __builtin_amdgcn_mfma_f32_32x32x16_bf16(kf0, qf[ks], s0, 0, 0, 0);
        s1 = __builtin_amdgcn_mfma_f32_32x32x16_bf16(kf1, qf[ks], s1, 0, 0, 0);
      }

      // ---- causal mask on the diagonal tile ----
      if (t == tlast) {
        const int qg = qw0 + ql;
#pragma unroll
        for (int r = 0; r < 16; ++r) {
          const int kr = t * 64 + (r & 3) + 8 * (r >> 2) + 4 * hi;
          if (kr > qg)      s0[r] = NEGBIG;
          if (kr + 32 > qg) s1[r] = NEGBIG;
        }
      }

      // ---- online softmax: lane-local reduce + one cross-half swap ----
      float pm = s0[0];
#pragma unroll
      for (int r = 1; r < 16; ++r) pm = fmaxf(pm, s0[r]);
#pragma unroll
      for (int r = 0; r < 16; ++r) pm = fmaxf(pm, s1[r]);
      pm = fmaxf(pm, __shfl_xor(pm, 32));

      const float mn = fmaxf(m, pm);
      const float sc = __builtin_exp2f(m - mn);
      m = mn;
      float rs = 0.0f;
#pragma unroll
      for (int r = 0; r < 16; ++r) { s0[r] = __builtin_exp2f(s0[r] - m); rs += s0[r]; }
#pragma unroll
      for (int r = 0; r < 16; ++r) { s1[r] = __builtin_exp2f(s1[r] - m); rs += s1[r]; }
      rs += __shfl_xor(rs, 32);
      l = l * sc + rs;
#pragma unroll
      for (int r = 0; r < 16; ++r) { oacc0[r] *= sc; oacc1[r] *= sc; }

      // ---- pack P to bf16 words: pwX[g*2+j] covers kv-off 8g+4hi+{2j,2j+1} ----
      unsigned int pw0[8], pw1[8];
#pragma unroll
      for (int g = 0; g < 4; ++g) {
#pragma unroll
        for (int j = 0; j < 2; ++j) {
          pw0[g * 2 + j] = cvtpk(s0[4 * g + 2 * j], s0[4 * g + 2 * j + 1]);
          pw1[g * 2 + j] = cvtpk(s1[4 * g + 2 * j], s1[4 * g + 2 * j + 1]);
        }
      }

      // ---- PV: O^T += V^T · P^T ; B-frag(ks) assembled via cross-half swap ----
#define PVSTEP(PW, KH, KS)                                                     \
  do {                                                                         \
    const unsigned int a0 = PW[(2 * (KH)) * 2 + 0], a1 = PW[(2 * (KH)) * 2 + 1];\
    const unsigned int b0 = PW[(2 * (KH) + 1) * 2 + 0],                        \
                       b1 = PW[(2 * (KH) + 1) * 2 + 1];                        \
    const unsigned int s0w = hi ? a0 : b0, s1w = hi ? a1 : b1;                 \
    const unsigned int r0 = __shfl_xor(s0w, 32), r1 = __shfl_xor(s1w, 32);     \
    const unsigned int k0 = hi ? b0 : a0, k1 = hi ? b1 : a1;                   \
    u32x4 fwu;                                                                 \
    fwu[0] = hi ? r0 : k0; fwu[1] = hi ? r1 : k1;                              \
    fwu[2] = hi ? k0 : r0; fwu[3] = hi ? k1 : r1;                              \
    const bf16x8 pf = __builtin_bit_cast(bf16x8, fwu);                         \
    const int cv = (((KS) * 2 + hi) ^ (ql & 7)) * 8;                           \
    const bf16x8 vf0 = *reinterpret_cast<const bf16x8*>(Vl + ql * 64 + cv);    \
    const bf16x8 vf1 = *reinterpret_cast<const bf16x8*>(Vl + (32 + ql) * 64 + cv);\
    oacc0 = __builtin_amdgcn_mfma_f32_32x32x16_bf16(vf0, pf, oacc0, 0, 0, 0);  \
    oacc1 = __builtin_amdgcn_mfma_f32_32x32x16_bf16(vf1, pf, oacc1, 0, 0, 0);  \
  } while (0)

      PVSTEP(pw0, 0, 0);
      PVSTEP(pw0, 1, 1);
      PVSTEP(pw1, 0, 2);
      PVSTEP(pw1, 1, 3);
#undef PVSTEP
    }

    __syncthreads();   // prefetch landed (vmcnt drain) + all reads of cur done
    cur ^= 1;
  }
#undef STAGE

  // ---- epilogue: per-wave LDS transpose, coalesced float4 stores ----
  float* Ow = smem + w * 1152;   // 32 q-rows x 36-float pitch
  const float invl = 1.0f / l;

#define EPI(OACC, SUBD)                                                        \
  do {                                                                         \
    _Pragma("unroll")                                                          \
    for (int r = 0; r < 16; ++r) {                                             \
      const int dl = (r & 3) + 8 * (r >> 2) + 4 * hi;                          \
      Ow[ql * 36 + dl] = OACC[r] * invl;                                       \
    }                                                                          \
    _Pragma("unroll")                                                          \
    for (int i = 0; i < 4; ++i) {                                              \
      const int qr = (lane >> 3) + i * 8;                                      \
      const int c4 = (lane & 7) * 4;                                           \
      float4 vv = *reinterpret_cast<const float4*>(Ow + qr * 36 + c4);         \
      *reinterpret_cast<float4*>(Oh + (size_t)(qw0 + qr) * DH + (SUBD) * 32 +  \
                                 c4) = vv;                                     \
    }                                                                          \
  } while (0)

  EPI(oacc0, 0);
  EPI(oacc1, 1);
#undef EPI
}

extern "C" void kernel_launch(void* const* d_in, const int* in_sizes, int n_in,
                              void* d_out, int out_size, void* d_ws, size_t ws_size,
                              hipStream_t stream) {
  const float* q = (const float*)d_in[0];
  const float* k = (const float*)d_in[1];
  const float* v = (const float*)d_in[2];
  // d_in[3] (causal tril mask) is implemented analytically, not read.
  float* out = (float*)d_out;

  const size_t per = (size_t)NH * SLEN * DH;   // elements per tensor
  ushort* wsK = (ushort*)d_ws;                 // ws_size >= 33.6MB (verified r2)
  ushort* wsV = wsK + per;

  prep_k<<<dim3(NT, NH), 256, 0, stream>>>(k, wsK);
  prep_v<<<dim3(NT, NH), 256, 0, stream>>>(v, wsV);
  attn_fwd3<<<dim3(NQB, NH), 512, 0, stream>>>(q, wsK, wsV, out);
}

// Round 5
// 100.345 us; speedup vs baseline: 3.9631x; 1.3112x over previous
//
#include <hip/hip_runtime.h>

#define SLEN 2048
#define DH 64
#define NH 64        // B*H
#define KVB 64
#define NT 32        // SLEN / KVB
#define NP 8         // complementary pairs per head (16 macro-tiles of 128 rows)
#define NEGBIG (-1e30f)
#define SCALE 0.18033688011112042f   // 0.125 * log2(e)  (softmax in exp2 domain)
#define DTHR 11.0f                   // defer-max threshold (log2 units, P<=2^11)

typedef __attribute__((ext_vector_type(8))) short bf16x8;
typedef __attribute__((ext_vector_type(8))) unsigned short u16x8;
typedef __attribute__((ext_vector_type(16))) float f32x16;
typedef __attribute__((ext_vector_type(4))) unsigned int u32x4;

__device__ __forceinline__ ushort f2bf(float f) {
  union { float f; unsigned int u; } v; v.f = f;
  unsigned int r = v.u + 0x7fffu + ((v.u >> 16) & 1u);  // RNE
  return (ushort)(r >> 16);
}

__device__ __forceinline__ unsigned int cvtpk(float lo, float hi2) {
  unsigned int r;
  asm("v_cvt_pk_bf16_f32 %0, %1, %2" : "=v"(r) : "v"(lo), "v"(hi2));
  return r;
}

// cross-half (lane ^ 32) reduce helpers — shfl_xor form (r3-verified).
// NOTE: permlane32_swap variants failed correctness in r4 (direction-sensitive
// PV exchange); re-try only as isolated A/B against a passing baseline.
__device__ __forceinline__ float xmaxh(float x) { return fmaxf(x, __shfl_xor(x, 32)); }
__device__ __forceinline__ float xsumh(float x) { return x + __shfl_xor(x, 32); }

__device__ __forceinline__ void gload16(const ushort* g, ushort* l) {
  __builtin_amdgcn_global_load_lds(
      (const __attribute__((address_space(1))) void*)g,
      (__attribute__((address_space(3))) void*)l, 16, 0, 0);
}

// ---- pre-pass: K -> bf16 tiles, chunk(r,c)=K[r][c*8..+7] at r*64 + ((c^(r&7))*8)
__global__ __launch_bounds__(256) void prep_k(const float* __restrict__ Kg,
                                              ushort* __restrict__ wsK) {
  const int tile = blockIdx.x, head = blockIdx.y, tid = threadIdx.x;
  const float* src = Kg + ((size_t)head * SLEN + (size_t)tile * KVB) * DH;
  ushort* dst = wsK + ((size_t)head * NT + tile) * (KVB * DH);
#pragma unroll
  for (int i = 0; i < 2; ++i) {
    const int id = tid + i * 256;
    const int r = id >> 3, c = id & 7;
    float4 a = *reinterpret_cast<const float4*>(src + r * DH + c * 8);
    float4 b = *reinterpret_cast<const float4*>(src + r * DH + c * 8 + 4);
    u16x8 t;
    t[0] = f2bf(a.x); t[1] = f2bf(a.y); t[2] = f2bf(a.z); t[3] = f2bf(a.w);
    t[4] = f2bf(b.x); t[5] = f2bf(b.y); t[6] = f2bf(b.z); t[7] = f2bf(b.w);
    *reinterpret_cast<u16x8*>(dst + r * DH + ((c ^ (r & 7)) * 8)) = t;
  }
}

// ---- pre-pass: V -> bf16 TRANSPOSED tiles, chunk(d,c)=V[c*8..+7][d] swizzled
__global__ __launch_bounds__(256) void prep_v(const float* __restrict__ Vg,
                                              ushort* __restrict__ wsV) {
  __shared__ float Vl[KVB][DH + 1];
  const int tile = blockIdx.x, head = blockIdx.y, tid = threadIdx.x;
  const float* src = Vg + ((size_t)head * SLEN + (size_t)tile * KVB) * DH;
#pragma unroll
  for (int i = 0; i < 4; ++i) {
    const int n = tid + i * 256;
    const int row = n >> 4, c4 = (n & 15) << 2;
    *reinterpret_cast<float4*>(&Vl[row][c4]) =
        *reinterpret_cast<const float4*>(src + row * DH + c4);
  }
  __syncthreads();
  ushort* dst = wsV + ((size_t)head * NT + tile) * (KVB * DH);
#pragma unroll
  for (int i = 0; i < 2; ++i) {
    const int id = tid + i * 256;
    const int d = id >> 3, c = id & 7;
    u16x8 t;
#pragma unroll
    for (int j = 0; j < 8; ++j) t[j] = f2bf(Vl[c * 8 + j][d]);
    *reinterpret_cast<u16x8*>(dst + d * DH + ((c ^ (d & 7)) * 8)) = t;
  }
}

// ---- one 64-kv tile for one 32-row q strip (swapped QK^T, 32x32x16) ----
__device__ __forceinline__ void strip_tile(
    const ushort* __restrict__ Kl, const ushort* __restrict__ Vl,
    const bf16x8* qf, f32x16& o0, f32x16& o1, float& m, float& l,
    int t, int tl, int q0, int ql, int hi) {
  // S^T[kv][q] = K · Q^T
  f32x16 s0 = (f32x16)0.0f, s1 = (f32x16)0.0f;
#pragma unroll
  for (int ks = 0; ks < 4; ++ks) {
    const int c = ((ks * 2 + hi) ^ (ql & 7)) * 8;
    bf16x8 kf0 = *reinterpret_cast<const bf16x8*>(Kl + ql * 64 + c);
    bf16x8 kf1 = *reinterpret_cast<const bf16x8*>(Kl + (32 + ql) * 64 + c);
    s0 = __builtin_amdgcn_mfma_f32_32x32x16_bf16(kf0, qf[ks], s0, 0, 0, 0);
    s1 = __builtin_amdgcn_mfma_f32_32x32x16_bf16(kf1, qf[ks], s1, 0, 0, 0);
  }

  if (t == tl) {   // causal mask on the diagonal tile
    const int qg = q0 + ql;
#pragma unroll
    for (int r = 0; r < 16; ++r) {
      const int kr = t * 64 + (r & 3) + 8 * (r >> 2) + 4 * hi;
      if (kr > qg)      s0[r] = NEGBIG;
      if (kr + 32 > qg) s1[r] = NEGBIG;
    }
  }

  // ---- tree max ----
  float tm[16];
#pragma unroll
  for (int r = 0; r < 16; ++r) tm[r] = fmaxf(s0[r], s1[r]);
#pragma unroll
  for (int st = 8; st >= 1; st >>= 1)
#pragma unroll
    for (int r = 0; r < 8; ++r)
      if (r < st) tm[r] = fmaxf(tm[r], tm[r + st]);
  const float pm = xmaxh(tm[0]);

  // ---- defer-max: rescale only when the running max grew materially ----
  if (__any(pm > m + DTHR)) {
    const float mn = fmaxf(m, pm);
    const float sc = __builtin_exp2f(m - mn);
    m = mn;
    l *= sc;
#pragma unroll
    for (int r = 0; r < 16; ++r) { o0[r] *= sc; o1[r] *= sc; }
  }

#pragma unroll
  for (int r = 0; r < 16; ++r) s0[r] = __builtin_exp2f(s0[r] - m);
#pragma unroll
  for (int r = 0; r < 16; ++r) s1[r] = __builtin_exp2f(s1[r] - m);

  // ---- tree sum ----
  float ts[16];
#pragma unroll
  for (int r = 0; r < 16; ++r) ts[r] = s0[r] + s1[r];
#pragma unroll
  for (int st = 8; st >= 1; st >>= 1)
#pragma unroll
    for (int r = 0; r < 8; ++r)
      if (r < st) ts[r] += ts[r + st];
  l += xsumh(ts[0]);

  // ---- pack P to bf16: pwX[g*2+j] covers kv-off 8g+4hi+{2j,2j+1} ----
  unsigned int pw0[8], pw1[8];
#pragma unroll
  for (int g = 0; g < 4; ++g)
#pragma unroll
    for (int j = 0; j < 2; ++j) {
      pw0[g * 2 + j] = cvtpk(s0[4 * g + 2 * j], s0[4 * g + 2 * j + 1]);
      pw1[g * 2 + j] = cvtpk(s1[4 * g + 2 * j], s1[4 * g + 2 * j + 1]);
    }

  // ---- PV: O^T += V^T · P^T ; fragment exchange via shfl_xor (r3-verified) ----
#pragma unroll
  for (int st = 0; st < 4; ++st) {
    const unsigned int* PW = (st < 2) ? pw0 : pw1;
    const int KH = st & 1;
    const unsigned int a0 = PW[4 * KH + 0], a1 = PW[4 * KH + 1];
    const unsigned int b0 = PW[4 * KH + 2], b1 = PW[4 * KH + 3];
    const unsigned int s0w = hi ? a0 : b0, s1w = hi ? a1 : b1;
    const unsigned int r0 = __shfl_xor(s0w, 32), r1 = __shfl_xor(s1w, 32);
    const unsigned int k0 = hi ? b0 : a0, k1 = hi ? b1 : a1;
    u32x4 fu;
    fu[0] = hi ? r0 : k0; fu[1] = hi ? r1 : k1;
    fu[2] = hi ? k0 : r0; fu[3] = hi ? k1 : r1;
    const bf16x8 pf = __builtin_bit_cast(bf16x8, fu);
    const int cv = ((st * 2 + hi) ^ (ql & 7)) * 8;
    const bf16x8 vf0 = *reinterpret_cast<const bf16x8*>(Vl + ql * 64 + cv);
    const bf16x8 vf1 = *reinterpret_cast<const bf16x8*>(Vl + (32 + ql) * 64 + cv);
    o0 = __builtin_amdgcn_mfma_f32_32x32x16_bf16(vf0, pf, o0, 0, 0, 0);
    o1 = __builtin_amdgcn_mfma_f32_32x32x16_bf16(vf1, pf, o1, 0, 0, 0);
  }
}

__device__ __forceinline__ void load_q(const float* Qh, int q0, int ql, int hi,
                                       bf16x8* qf) {
  const float* qrow = Qh + (size_t)(q0 + ql) * DH;
#pragma unroll
  for (int ks = 0; ks < 4; ++ks) {
    const int d0 = ks * 16 + hi * 8;
    float4 a = *reinterpret_cast<const float4*>(qrow + d0);
    float4 b = *reinterpret_cast<const float4*>(qrow + d0 + 4);
    bf16x8 t;
    t[0] = (short)f2bf(a.x * SCALE); t[1] = (short)f2bf(a.y * SCALE);
    t[2] = (short)f2bf(a.z * SCALE); t[3] = (short)f2bf(a.w * SCALE);
    t[4] = (short)f2bf(b.x * SCALE); t[5] = (short)f2bf(b.y * SCALE);
    t[6] = (short)f2bf(b.z * SCALE); t[7] = (short)f2bf(b.w * SCALE);
    qf[ks] = t;
  }
}

// per-wave epilogue half: LDS transpose + coalesced float4 stores
__device__ __forceinline__ void epi(float* Ow, float* Oh, const f32x16& o,
                                    float invl, int q0, int subd, int lane) {
  const int ql = lane & 31, hi = lane >> 5;
#pragma unroll
  for (int g = 0; g < 4; ++g) {
    float4 vv = make_float4(o[4 * g] * invl, o[4 * g + 1] * invl,
                            o[4 * g + 2] * invl, o[4 * g + 3] * invl);
    *reinterpret_cast<float4*>(Ow + ql * 36 + 8 * g + 4 * hi) = vv;
  }
#pragma unroll
  for (int i = 0; i < 4; ++i) {
    const int qr = (lane >> 3) + i * 8;
    const int c4 = (lane & 7) * 4;
    float4 vv = *reinterpret_cast<const float4*>(Ow + qr * 36 + c4);
    *reinterpret_cast<float4*>(Oh + (size_t)(q0 + qr) * DH + subd * 32 + c4) = vv;
  }
}

// ---- main: paired q-macro-tiles (p, 15-p) share one staged KV stream ----
__global__ __launch_bounds__(256, 2) void attn_fwd5(
    const float* __restrict__ Qg, const ushort* __restrict__ wsK,
    const ushort* __restrict__ wsV, float* __restrict__ Og) {
  __shared__ __align__(16) float smem[8192];   // 32KB: 2 x (K 8KB | V 8KB)
  ushort* stg = (ushort*)smem;

  const int p    = blockIdx.x;
  const int head = blockIdx.y;
  const int tid  = threadIdx.x;
  const int w    = tid >> 6;
  const int lane = tid & 63;
  const int hi   = lane >> 5;
  const int ql   = lane & 31;

  const int q0A = p * 128 + w * 32;          // short strip (early diag)
  const int q0B = (15 - p) * 128 + w * 32;   // long strip
  const int tlA = q0A >> 6;
  const int tlB = q0B >> 6;
  const int nt  = 32 - 2 * p;                // staged tiles (covers tlB+1)

  const float*  Qh    = Qg + (size_t)head * SLEN * DH;
  float*        Oh    = Og + (size_t)head * SLEN * DH;
  const ushort* kbase = wsK + (size_t)head * (NT * KVB * DH);
  const ushort* vbase = wsV + (size_t)head * (NT * KVB * DH);

#define STAGE(buf, t)                                                          \
  do {                                                                         \
    const size_t tb_ = (size_t)(t) * 4096;                                     \
    gload16(kbase + tb_ + tid * 8,        stg + (buf) * 8192 + tid * 8);       \
    gload16(kbase + tb_ + 2048 + tid * 8, stg + (buf) * 8192 + 2048 + tid * 8);\
    gload16(vbase + tb_ + tid * 8,        stg + (buf) * 8192 + 4096 + tid * 8);\
    gload16(vbase + tb_ + 2048 + tid * 8,                                      \
            stg + (buf) * 8192 + 6144 + tid * 8);                              \
  } while (0)

  STAGE(0, 0);

  bf16x8 qfA[4], qfB[4];
  load_q(Qh, q0A, ql, hi, qfA);
  load_q(Qh, q0B, ql, hi, qfB);

  f32x16 oA0 = (f32x16)0.0f, oA1 = (f32x16)0.0f;
  f32x16 oB0 = (f32x16)0.0f, oB1 = (f32x16)0.0f;
  float mA = -3.0e38f, lA = 0.0f, mB = -3.0e38f, lB = 0.0f;

  __syncthreads();   // tile 0 resident

  int cur = 0;
  for (int t = 0; t < nt; ++t) {
    if (t + 1 < nt) STAGE(cur ^ 1, t + 1);

    const ushort* Kl = stg + cur * 8192;
    const ushort* Vl = Kl + 4096;

    if (t <= tlB) strip_tile(Kl, Vl, qfB, oB0, oB1, mB, lB, t, tlB, q0B, ql, hi);
    if (t <= tlA) strip_tile(Kl, Vl, qfA, oA0, oA1, mA, lA, t, tlA, q0A, ql, hi);

    __syncthreads();
    cur ^= 1;
  }
#undef STAGE

  // ---- epilogue (per-wave private LDS region; no inter-wave hazard) ----
  float* Ow = smem + w * 1152;   // 32 rows x 36-float pitch
  const float iA = 1.0f / lA, iB = 1.0f / lB;
  epi(Ow, Oh, oA0, iA, q0A, 0, lane);
  epi(Ow, Oh, oA1, iA, q0A, 1, lane);
  epi(Ow, Oh, oB0, iB, q0B, 0, lane);
  epi(Ow, Oh, oB1, iB, q0B, 1, lane);
}

extern "C" void kernel_launch(void* const* d_in, const int* in_sizes, int n_in,
                              void* d_out, int out_size, void* d_ws, size_t ws_size,
                              hipStream_t stream) {
  const float* q = (const float*)d_in[0];
  const float* k = (const float*)d_in[1];
  const float* v = (const float*)d_in[2];
  // d_in[3] (causal tril mask) is implemented analytically, not read.
  float* out = (float*)d_out;

  const size_t per = (size_t)NH * SLEN * DH;   // elements per tensor
  ushort* wsK = (ushort*)d_ws;                 // ws_size >= 33.6MB (verified)
  ushort* wsV = wsK + per;

  prep_k<<<dim3(NT, NH), 256, 0, stream>>>(k, wsK);
  prep_v<<<dim3(NT, NH), 256, 0, stream>>>(v, wsV);
  attn_fwd5<<<dim3(NP, NH), 256, 0, stream>>>(q, wsK, wsV, out);
}